// Round 1
// baseline (737.993 us; speedup 1.0000x reference)
//
#include <hip/hip_runtime.h>
#include <math.h>

// Problem constants (match reference)
#define BATCH 16384
#define DNUM  13
#define SNUM  26
#define FEAT  100000
#define KDIM  64

// One 64-lane wave per batch row; lane l owns latent dim k = l.
// V-row gathers are coalesced 256B transactions (64 lanes x 4B contiguous).
__global__ __launch_bounds__(256) void fm_kernel(
    const float* __restrict__ dense,   // [B, D]
    const int*   __restrict__ sparse,  // [B, S]
    const float* __restrict__ w,       // [TOTAL, 1]
    const float* __restrict__ V,       // [TOTAL, K]
    const float* __restrict__ bias,    // [1]
    float* __restrict__ out)           // [B]
{
    const int gtid = blockIdx.x * blockDim.x + threadIdx.x;
    const int row  = gtid >> 6;          // wave id = batch row
    const int lane = threadIdx.x & 63;
    if (row >= BATCH) return;

    // Lanes 0..S-1 each hold one global gather index for this row.
    int myidx = 0;
    if (lane < SNUM) {
        myidx = sparse[row * SNUM + lane] + DNUM + lane * FEAT;
    }

    float xv = 0.0f, x2v2 = 0.0f, lin = 0.0f;

    // ---- dense part: x_d * V[d, lane] ----
    #pragma unroll
    for (int d = 0; d < DNUM; ++d) {
        float xd = dense[row * DNUM + d];   // wave-uniform broadcast load
        float v  = V[d * KDIM + lane];      // hot in L1/L2 (13 rows)
        xv   += xd * v;
        x2v2 += xd * xd * v * v;
    }
    if (lane < DNUM) {
        lin += dense[row * DNUM + lane] * w[lane];
    }

    // ---- sparse part: gather S rows of V ----
    #pragma unroll
    for (int s = 0; s < SNUM; ++s) {
        int idx = __shfl(myidx, s);                 // broadcast index to all lanes
        float v = V[(long long)idx * KDIM + lane];  // coalesced 256B row read
        xv   += v;
        x2v2 += v * v;
    }
    if (lane < SNUM) {
        lin += w[myidx];                            // scattered 4B gathers, lanes 0..25
    }

    // ---- combine: per-lane partial = 0.5*(xv^2 - x2v2) + lin_partial ----
    float partial = 0.5f * (xv * xv - x2v2) + lin;

    // 64-lane butterfly reduction
    #pragma unroll
    for (int off = 32; off > 0; off >>= 1)
        partial += __shfl_down(partial, off);

    if (lane == 0) {
        float z = partial + bias[0];
        out[row] = 1.0f / (1.0f + expf(-z));
    }
}

extern "C" void kernel_launch(void* const* d_in, const int* in_sizes, int n_in,
                              void* d_out, int out_size, void* d_ws, size_t ws_size,
                              hipStream_t stream) {
    const float* dense  = (const float*)d_in[0];
    const int*   sparse = (const int*)d_in[1];
    const float* w      = (const float*)d_in[2];
    const float* V      = (const float*)d_in[3];
    const float* bias   = (const float*)d_in[4];
    float* out = (float*)d_out;

    // One wave per row, 4 waves per 256-thread block.
    const int waves_per_block = 256 / 64;
    const int grid = (BATCH + waves_per_block - 1) / waves_per_block;
    fm_kernel<<<grid, 256, 0, stream>>>(dense, sparse, w, V, bias, out);
}